// Round 1
// baseline (753.407 us; speedup 1.0000x reference)
//
#include <hip/hip_runtime.h>
#include <math.h>

#define HIDDEN 4096
#define NEXP   128
#define TOPK   8
#define BM     64
#define BK     32
#define SA     68    // padded LDS stride for A tile (floats, mult of 4 for float4 align)
#define SB     132   // padded LDS stride for W tile
#define SS     132   // padded stride for score rows in epilogue

// smem usage:
//   GEMM phase: As[BK][SA] = 2176 f, Bs[BK][SB] = 4224 f  -> 6400 floats
//   epilogue  : Ss[BM][SS] = 8448 floats (aliases the GEMM buffers)
#define SMEM_FLOATS 8448

__global__ __launch_bounds__(256, 1) void router_kernel(
    const float* __restrict__ h,     // [T, HIDDEN]
    const float* __restrict__ w,     // [NEXP, HIDDEN]
    const float* __restrict__ bias,  // [NEXP]
    float* __restrict__ out,         // [T*8] indices (as float) then [T*8] weights
    int T)
{
    __shared__ float smem[SMEM_FLOATS];
    float* As = smem;            // [BK][SA]  transposed: As[k][token]
    float* Bs = smem + BK * SA;  // [BK][SB]  transposed: Bs[k][expert]

    const int tid  = threadIdx.x;
    const int row0 = blockIdx.x * BM;
    const int tn   = tid & 15;   // expert group: experts {4tn..4tn+3} u {64+4tn..+3}
    const int tm   = tid >> 4;   // token group: tokens 4tm..4tm+3  (0..15)

    float acc[4][8];
#pragma unroll
    for (int i = 0; i < 4; ++i)
#pragma unroll
        for (int j = 0; j < 8; ++j) acc[i][j] = 0.0f;

    for (int k0 = 0; k0 < HIDDEN; k0 += BK) {
        __syncthreads();  // previous iteration's reads done before overwrite
        // ---- stage A: 64 rows x 32 k = 512 float4, transposed into As[k][m]
#pragma unroll
        for (int i = 0; i < 2; ++i) {
            const int id = tid + 256 * i;
            const int r  = id >> 3;      // token row 0..63
            const int kq = id & 7;       // float4 index along k
            const float4 v = *(const float4*)(h + (size_t)(row0 + r) * HIDDEN + k0 + 4 * kq);
            As[(4 * kq + 0) * SA + r] = v.x;
            As[(4 * kq + 1) * SA + r] = v.y;
            As[(4 * kq + 2) * SA + r] = v.z;
            As[(4 * kq + 3) * SA + r] = v.w;
        }
        // ---- stage B: 128 rows x 32 k = 1024 float4, transposed into Bs[k][e]
#pragma unroll
        for (int i = 0; i < 4; ++i) {
            const int id = tid + 256 * i;
            const int r  = id >> 3;      // expert row 0..127
            const int kq = id & 7;
            const float4 v = *(const float4*)(w + (size_t)r * HIDDEN + k0 + 4 * kq);
            Bs[(4 * kq + 0) * SB + r] = v.x;
            Bs[(4 * kq + 1) * SB + r] = v.y;
            Bs[(4 * kq + 2) * SB + r] = v.z;
            Bs[(4 * kq + 3) * SB + r] = v.w;
        }
        __syncthreads();
        // ---- inner product over this K chunk
#pragma unroll 8
        for (int k = 0; k < BK; ++k) {
            const float4 a  = *(const float4*)(As + k * SA + 4 * tm);
            const float4 b0 = *(const float4*)(Bs + k * SB + 4 * tn);
            const float4 b1 = *(const float4*)(Bs + k * SB + 64 + 4 * tn);
            const float av[4] = {a.x, a.y, a.z, a.w};
            const float bv[8] = {b0.x, b0.y, b0.z, b0.w, b1.x, b1.y, b1.z, b1.w};
#pragma unroll
            for (int i = 0; i < 4; ++i)
#pragma unroll
                for (int j = 0; j < 8; ++j)
                    acc[i][j] = fmaf(av[i], bv[j], acc[i][j]);
        }
    }

    // ---- write logits to shared score buffer (aliases As/Bs)
    __syncthreads();
    float* Ss = smem;  // [BM][SS]
#pragma unroll
    for (int i = 0; i < 4; ++i) {
        const int t = 4 * tm + i;
        *(float4*)(Ss + t * SS + 4 * tn)      = make_float4(acc[i][0], acc[i][1], acc[i][2], acc[i][3]);
        *(float4*)(Ss + t * SS + 64 + 4 * tn) = make_float4(acc[i][4], acc[i][5], acc[i][6], acc[i][7]);
    }
    __syncthreads();

    // ---- top-k epilogue: wave w handles tokens w, w+4, ...
    const int wave = tid >> 6;
    const int lane = tid & 63;
    const float bb0 = bias[lane];
    const float bb1 = bias[lane + 64];

    for (int t = wave; t < BM; t += 4) {
        const float lg0 = Ss[t * SS + lane];
        const float lg1 = Ss[t * SS + 64 + lane];
        const float s0 = 1.0f / (1.0f + expf(-lg0));  // raw sigmoid score
        const float s1 = 1.0f / (1.0f + expf(-lg1));
        float c0 = s0 + bb0;                          // bias-corrected, used for selection
        float c1 = s1 + bb1;

        int   sel_i[TOPK];
        float sel_r[TOPK];
        float rsum = 0.0f;
#pragma unroll
        for (int j = 0; j < TOPK; ++j) {
            // local candidate: tie -> smaller expert index (lane < lane+64)
            const bool take0 = (c0 >= c1);
            float v  = take0 ? c0 : c1;
            float rr = take0 ? s0 : s1;
            int   ii = take0 ? lane : lane + 64;
            // 64-lane butterfly argmax, lexicographic (value desc, index asc)
#pragma unroll
            for (int off = 32; off > 0; off >>= 1) {
                const float ov  = __shfl_xor(v, off, 64);
                const float orr = __shfl_xor(rr, off, 64);
                const int   oi  = __shfl_xor(ii, off, 64);
                if (ov > v || (ov == v && oi < ii)) { v = ov; rr = orr; ii = oi; }
            }
            sel_i[j] = ii;
            sel_r[j] = rr;
            rsum += rr;
            if (ii == lane)      c0 = -__builtin_inff();
            if (ii == lane + 64) c1 = -__builtin_inff();
        }
        if (lane == 0) {
            const float inv = 1.0f / (rsum + 1e-20f);
            const size_t tok = (size_t)(row0 + t);
#pragma unroll
            for (int j = 0; j < TOPK; ++j) {
                out[tok * TOPK + j]                      = (float)sel_i[j];
                out[(size_t)T * TOPK + tok * TOPK + j]   = sel_r[j] * inv;
            }
        }
    }
}

extern "C" void kernel_launch(void* const* d_in, const int* in_sizes, int n_in,
                              void* d_out, int out_size, void* d_ws, size_t ws_size,
                              hipStream_t stream) {
    const float* h    = (const float*)d_in[0];
    const float* w    = (const float*)d_in[1];
    const float* bias = (const float*)d_in[2];
    float* out = (float*)d_out;
    const int T = in_sizes[0] / HIDDEN;  // 16384

    dim3 grid(T / BM);   // 256 blocks
    dim3 block(256);
    hipLaunchKernelGGL(router_kernel, grid, block, 0, stream, h, w, bias, out, T);
}